// Round 1
// baseline (1219.529 us; speedup 1.0000x reference)
//
#include <hip/hip_runtime.h>
#include <cstdint>
#include <cstddef>

// Problem constants
#define BROWS 8192
#define DIM   2048
#define K2    4096      // 2*DIM (GEMM K)
#define N4    8192      // 4*DIM (GEMM N)

typedef _Float16 f16x8 __attribute__((ext_vector_type(8)));
typedef float    f32x4 __attribute__((ext_vector_type(4)));

#define GLOBAL_AS __attribute__((address_space(1)))
#define LDS_AS    __attribute__((address_space(3)))

__device__ __forceinline__ void gload_lds16(const void* g, void* l) {
    __builtin_amdgcn_global_load_lds((const GLOBAL_AS void*)g, (LDS_AS void*)l, 16, 0, 0);
}

// ---------------------------------------------------------------------------
// pack_A: A[r][k] (f16, row-major, K contiguous) = [x | h] cast to fp16.
// Each thread converts 8 contiguous elements (2x float4 load, 1x 16B store).
// ---------------------------------------------------------------------------
__global__ __launch_bounds__(256) void pack_A_kernel(const float* __restrict__ x,
                                                     const float* __restrict__ h,
                                                     _Float16* __restrict__ A) {
    const size_t i    = (size_t)blockIdx.x * 256 + threadIdx.x;
    const size_t base = i * 8;               // element index in [0, 8192*4096)
    const size_t r    = base >> 12;          // / 4096
    const size_t k    = base & 4095;
    const float* src  = (k < 2048) ? (x + r * 2048 + k) : (h + r * 2048 + (k - 2048));
    const float4 f0 = ((const float4*)src)[0];
    const float4 f1 = ((const float4*)src)[1];
    f16x8 o;
    o[0] = (_Float16)f0.x; o[1] = (_Float16)f0.y; o[2] = (_Float16)f0.z; o[3] = (_Float16)f0.w;
    o[4] = (_Float16)f1.x; o[5] = (_Float16)f1.y; o[6] = (_Float16)f1.z; o[7] = (_Float16)f1.w;
    *(f16x8*)(A + base) = o;
}

// ---------------------------------------------------------------------------
// pack_W: Wp[j][k] (f16) = W_g[d][k] with the gate-interleaved column order
//   g = (j>>4)&3,  d = 16*(j>>6) + (j&15)
// so a 16-wide MFMA N-fragment is a single gate and fragments g=0..3 of one
// wave cover i/f/o/z for the same 16 d values.
// ---------------------------------------------------------------------------
__global__ __launch_bounds__(256) void pack_W_kernel(const float* __restrict__ Wi,
                                                     const float* __restrict__ Wf,
                                                     const float* __restrict__ Wo,
                                                     const float* __restrict__ Wz,
                                                     _Float16* __restrict__ Wp) {
    const size_t i    = (size_t)blockIdx.x * 256 + threadIdx.x;
    const size_t base = i * 8;
    const size_t j    = base >> 12;
    const size_t k    = base & 4095;
    const int    g    = (int)((j >> 4) & 3);
    const size_t d    = 16 * (j >> 6) + (j & 15);
    const float* Ws   = (g == 0) ? Wi : (g == 1) ? Wf : (g == 2) ? Wo : Wz;
    const float* src  = Ws + d * 4096 + k;
    const float4 f0 = ((const float4*)src)[0];
    const float4 f1 = ((const float4*)src)[1];
    f16x8 o;
    o[0] = (_Float16)f0.x; o[1] = (_Float16)f0.y; o[2] = (_Float16)f0.z; o[3] = (_Float16)f0.w;
    o[4] = (_Float16)f1.x; o[5] = (_Float16)f1.y; o[6] = (_Float16)f1.z; o[7] = (_Float16)f1.w;
    *(f16x8*)(Wp + base) = o;
}

// ---------------------------------------------------------------------------
// Fused GEMM (NT, f16 inputs, fp32 accum) + sLSTM epilogue.
// Tile 128x128, BK=32, 256 threads = 4 waves in 2x2 wave grid; each wave
// computes 64 rows x (16 d x 4 gates) via 4x4 grid of 16x16x32 MFMA.
// Staging via global_load_lds width=16 (m97 structure, 2-barrier K-loop).
// ---------------------------------------------------------------------------
__global__ __launch_bounds__(256) void slstm_gemm_kernel(
    const _Float16* __restrict__ A, const _Float16* __restrict__ W,
    const float* __restrict__ c_in, const float* __restrict__ n_in,
    const float* __restrict__ m_in,
    const float* __restrict__ bi_p, const float* __restrict__ bf_p,
    const float* __restrict__ bo_p, const float* __restrict__ bz_p,
    float* __restrict__ out)
{
    __shared__ _Float16 As[128 * 32];   // 8 KB, rows of 32 halves (64 B), no pad
    __shared__ _Float16 Bs[128 * 32];   // 8 KB

    const int tid  = threadIdx.x;
    const int lane = tid & 63;
    const int w    = tid >> 6;      // wave 0..3
    const int wm   = w >> 1;        // wave M index (0..1)
    const int wn   = w & 1;         // wave N index (0..1)
    const int bx   = blockIdx.x;    // N tile (0..63)
    const int by   = blockIdx.y;    // M tile (0..63)
    const int row0 = by * 128;
    const int j0   = bx * 128;

    // --- staging addressing: 512 16B chunks per tile; chunk c = cb + lane,
    // cb = t*256 + w*64; row = c>>2, col halves = (c&3)*8.
    const int cb0 = w * 64;
    const int cb1 = 256 + w * 64;
    const int lr  = lane >> 2;          // chunk row within group of 64 chunks
    const int lc  = (lane & 3) * 8;     // half offset within row
    const _Float16* gA0 = A + (size_t)(row0 + cb0 / 4 + lr) * K2 + lc;
    const _Float16* gA1 = A + (size_t)(row0 + cb1 / 4 + lr) * K2 + lc;
    const _Float16* gB0 = W + (size_t)(j0 + cb0 / 4 + lr) * K2 + lc;
    const _Float16* gB1 = W + (size_t)(j0 + cb1 / 4 + lr) * K2 + lc;
    _Float16* lA0 = &As[cb0 * 8];       // wave-uniform LDS bases (+lane*16 by HW)
    _Float16* lA1 = &As[cb1 * 8];
    _Float16* lB0 = &Bs[cb0 * 8];
    _Float16* lB1 = &Bs[cb1 * 8];

    // --- fragment read addressing
    const int col16 = lane & 15;
    const int quad  = lane >> 4;
    const _Float16* aRd = &As[(wm * 64 + col16) * 32 + quad * 8];  // + mi*16*32
    const _Float16* bRd = &Bs[(wn * 64 + col16) * 32 + quad * 8];  // + g*16*32

    f32x4 acc[4][4] = {};   // [mi][gate]

    for (int kt = 0; kt < K2 / 32; ++kt) {
        const size_t ko = (size_t)kt * 32;
        gload_lds16(gA0 + ko, lA0);
        gload_lds16(gA1 + ko, lA1);
        gload_lds16(gB0 + ko, lB0);
        gload_lds16(gB1 + ko, lB1);
        __syncthreads();   // drains vmcnt(0): LDS tile ready

        f16x8 af[4], bf[4];
#pragma unroll
        for (int mi = 0; mi < 4; ++mi) af[mi] = *(const f16x8*)(aRd + mi * 512);
#pragma unroll
        for (int g = 0; g < 4; ++g)    bf[g] = *(const f16x8*)(bRd + g * 512);
#pragma unroll
        for (int mi = 0; mi < 4; ++mi)
#pragma unroll
            for (int g = 0; g < 4; ++g)
                acc[mi][g] = __builtin_amdgcn_mfma_f32_16x16x32_f16(af[mi], bf[g], acc[mi][g], 0, 0, 0);
        __syncthreads();   // all reads done before next tile overwrites
    }

    // --- epilogue: lane-local i/f/o/z for (row, d); fully in registers.
    // D frag mapping: col = lane&15 (-> d), row = quad*4 + reg.
    const int   d   = (2 * bx + wn) * 16 + col16;
    const float biv = bi_p[d];
    const float bfv = bf_p[d];
    const float bov = bo_p[d];
    const float bzv = bz_p[d];
    const size_t BD = (size_t)BROWS * DIM;

#pragma unroll
    for (int mi = 0; mi < 4; ++mi) {
        const int rowb = row0 + wm * 64 + mi * 16 + quad * 4;
#pragma unroll
        for (int r = 0; r < 4; ++r) {
            const size_t idx = (size_t)(rowb + r) * DIM + d;
            const float it = acc[mi][0][r] + biv;
            const float ft = acc[mi][1][r] + bfv;
            const float ot = acc[mi][2][r] + bov;
            const float zt = acc[mi][3][r] + bzv;
            const float cv = c_in[idx];
            const float nv = n_in[idx];
            const float mv = m_in[idx];
            const float z    = tanhf(zt);
            const float mnew = fmaxf(ft + mv, it);
            const float iv   = __expf(it - mnew);
            const float fv   = __expf(ft + mv - mnew);
            const float cnew = fv * cv + iv * z;
            const float nnew = fv * nv + iv;
            const float sig  = 1.0f / (1.0f + __expf(-ot));
            const float hnew = sig * cnew / (nnew + 1e-6f);
            out[idx]          = hnew;
            out[BD + idx]     = cnew;
            out[2 * BD + idx] = nnew;
            out[3 * BD + idx] = mnew;
        }
    }
}

// ---------------------------------------------------------------------------
extern "C" void kernel_launch(void* const* d_in, const int* in_sizes, int n_in,
                              void* d_out, int out_size, void* d_ws, size_t ws_size,
                              hipStream_t stream) {
    const float* x  = (const float*)d_in[0];
    const float* h  = (const float*)d_in[1];
    const float* cp = (const float*)d_in[2];
    const float* np_ = (const float*)d_in[3];
    const float* mp = (const float*)d_in[4];
    const float* Wi = (const float*)d_in[5];
    const float* bi = (const float*)d_in[6];
    const float* Wf = (const float*)d_in[7];
    const float* bf = (const float*)d_in[8];
    const float* Wo = (const float*)d_in[9];
    const float* bo = (const float*)d_in[10];
    const float* Wz = (const float*)d_in[11];
    const float* bz = (const float*)d_in[12];

    _Float16* A  = (_Float16*)d_ws;                                     // 64 MB
    _Float16* Wp = (_Float16*)((char*)d_ws + (size_t)BROWS * K2 * 2);   // 64 MB

    // 8192*4096 / 8 elems-per-thread / 256 threads = 16384 blocks
    pack_A_kernel<<<16384, 256, 0, stream>>>(x, h, A);
    pack_W_kernel<<<16384, 256, 0, stream>>>(Wi, Wf, Wo, Wz, Wp);

    dim3 grid(N4 / 128, BROWS / 128);   // 64 x 64
    slstm_gemm_kernel<<<grid, 256, 0, stream>>>(A, Wp, cp, np_, mp,
                                                bi, bf, bo, bz, (float*)d_out);
}